// Round 6
// baseline (77.917 us; speedup 1.0000x reference)
//
#include <hip/hip_runtime.h>
#include <math.h>

typedef float v2f __attribute__((ext_vector_type(2)));

#define N_POINTS 32768
#define NUM_EMBED 8192
#define NPAIRS 4096
#define PPT 8                                // points per thread (amortizes LDS broadcasts)
#define CSTRIDE 4096                         // 64*64, channel stride in z [B,C,H,W]

// ---------------- kernel A: build pair-interleaved codebook + ee (exact XLA arithmetic)
__global__ void vq_prep_kernel(const float4* __restrict__ E,
                               v2f* __restrict__ Epk, v2f* __restrict__ eev) {
    int p = blockIdx.x * 256 + threadIdx.x;
    if (p < NPAIRS) {
        float4 a = E[2 * p];
        float4 b = E[2 * p + 1];
        Epk[4 * p + 0] = (v2f){a.x, b.x};
        Epk[4 * p + 1] = (v2f){a.y, b.y};
        Epk[4 * p + 2] = (v2f){a.z, b.z};
        Epk[4 * p + 3] = (v2f){a.w, b.w};
        float ea = __fmul_rn(a.x, a.x);
        ea = __fadd_rn(ea, __fmul_rn(a.y, a.y));
        ea = __fadd_rn(ea, __fmul_rn(a.z, a.z));
        ea = __fadd_rn(ea, __fmul_rn(a.w, a.w));
        float eb = __fmul_rn(b.x, b.x);
        eb = __fadd_rn(eb, __fmul_rn(b.y, b.y));
        eb = __fadd_rn(eb, __fmul_rn(b.z, b.z));
        eb = __fadd_rn(eb, __fmul_rn(b.w, b.w));
        eev[p] = (v2f){ea, eb};
    }
}

// packed f32 ops forced via inline asm (per-half IEEE rn, bit-identical to scalar chain)
__device__ __forceinline__ v2f pk_add(v2f a, v2f b) {
    v2f d; asm("v_pk_add_f32 %0, %1, %2" : "=v"(d) : "v"(a), "v"(b)); return d;
}
__device__ __forceinline__ v2f pk_mul(v2f a, v2f b) {
    v2f d; asm("v_pk_mul_f32 %0, %1, %2" : "=v"(d) : "v"(a), "v"(b)); return d;
}
__device__ __forceinline__ v2f pk_fma(v2f a, v2f b, v2f c) {
    v2f d; asm("v_pk_fma_f32 %0, %1, %2, %3" : "=v"(d) : "v"(a), "v"(b), "v"(c)); return d;
}

// ---------------- kernel B: per (point, chunk) PAIR-granularity argmin
// Tracks (min value, pair id) with strict < (first pair wins). 8 points/thread so each
// broadcast LDS read feeds 8 evaluations (LDS return BW was the round-5 wall).
template<int CH>
__global__ __launch_bounds__(256) void vq_partial_kernel(
        const float* __restrict__ z, const v2f* __restrict__ Epk,
        const v2f* __restrict__ eev,
        float* __restrict__ wd, int* __restrict__ wp) {
    constexpr int PAIRS = NPAIRS / CH;
    __shared__ alignas(16) v2f sE[PAIRS * 4];
    __shared__ alignas(16) v2f see[PAIRS];

    const int c = blockIdx.y;

    // ---- stage chunk slice to LDS (coalesced float4 vector loads)
    {
        const float4* gE = (const float4*)(Epk + (size_t)c * PAIRS * 4); // PAIRS*2 float4
        float4* sw = (float4*)sE;
        #pragma unroll
        for (int i = 0; i < (PAIRS * 2) / 256; ++i)
            sw[i * 256 + threadIdx.x] = gE[i * 256 + threadIdx.x];
        if (threadIdx.x < PAIRS / 2) {
            ((float4*)see)[threadIdx.x] =
                ((const float4*)(eev + (size_t)c * PAIRS))[threadIdx.x];
        }
    }

    const int n0 = blockIdx.x * (256 * PPT) + threadIdx.x;

    // ---- load PPT points; zz via mul + sequential adds (matches reference exactly)
    v2f zv[PPT][4], zzv[PPT];
    #pragma unroll
    for (int p = 0; p < PPT; ++p) {
        int n = n0 + p * 256;
        int b = n >> 12, hw = n & 4095;
        const float* zp = z + b * 16384 + hw;
        float a0 = zp[0], a1 = zp[CSTRIDE], a2 = zp[2 * CSTRIDE], a3 = zp[3 * CSTRIDE];
        float zz = __fmul_rn(a0, a0);
        zz = __fadd_rn(zz, __fmul_rn(a1, a1));
        zz = __fadd_rn(zz, __fmul_rn(a2, a2));
        zz = __fadd_rn(zz, __fmul_rn(a3, a3));
        zv[p][0] = (v2f){a0, a0}; zv[p][1] = (v2f){a1, a1};
        zv[p][2] = (v2f){a2, a2}; zv[p][3] = (v2f){a3, a3};
        zzv[p] = (v2f){zz, zz};
    }
    const v2f m2v = {-2.0f, -2.0f};

    __syncthreads();

    float bd[PPT]; int bp[PPT];
    #pragma unroll
    for (int p = 0; p < PPT; ++p) { bd[p] = __builtin_inff(); bp[p] = 0; }

    const float4* sE4 = (const float4*)sE;
    #pragma unroll 2
    for (int t = 0; t < PAIRS; ++t) {
        // uniform LDS reads -> hardware broadcast, no bank conflicts
        float4 E01 = sE4[2 * t];       // {e0.lo,e0.hi, e1.lo,e1.hi}
        float4 E23 = sE4[2 * t + 1];   // {e2.lo,e2.hi, e3.lo,e3.hi}
        v2f ee2 = see[t];
        v2f e0 = {E01.x, E01.y};
        v2f e1 = {E01.z, E01.w};
        v2f e2 = {E23.x, E23.y};
        v2f e3 = {E23.z, E23.w};
        #pragma unroll
        for (int p = 0; p < PPT; ++p) {
            // per-half arithmetic identical to the scalar reference chain:
            v2f szz = pk_add(zzv[p], ee2);        // zz + ee_j         (rn)
            v2f dot = pk_mul(zv[p][0], e0);       // z0*e0             (rn)
            dot = pk_fma(zv[p][1], e1, dot);      // ascending-k fma chain
            dot = pk_fma(zv[p][2], e2, dot);
            dot = pk_fma(zv[p][3], e3, dot);
            v2f d2 = pk_fma(m2v, dot, szz);       // (zz+ee) - 2*dot (2*dot exact)
            float md = fminf(d2.x, d2.y);         // exact selection (no NaNs)
            if (md < bd[p]) { bd[p] = md; bp[p] = t; }  // strict <: first pair wins
        }
    }

    const int pbase = c * PAIRS;
    #pragma unroll
    for (int p = 0; p < PPT; ++p) {
        int n = n0 + p * 256;
        wd[c * N_POINTS + n] = bd[p];
        wp[c * N_POINTS + n] = pbase + bp[p];    // global pair id
    }
}

// ---------------- kernel C: combine chunks, resolve pair exactly, write outputs
template<int CH>
__global__ __launch_bounds__(256) void vq_finalize_kernel(
        const float* __restrict__ z, const float4* __restrict__ E,
        const float* __restrict__ wd, const int* __restrict__ wp,
        float* __restrict__ out, double* __restrict__ partial) {
    __shared__ double sdata[256];
    int n = blockIdx.x * 256 + threadIdx.x;
    float bestd = __builtin_inff();
    int bpair = 0;
    #pragma unroll 4
    for (int c = 0; c < CH; ++c) {               // ascending chunk + strict < -> first pair
        float d = wd[c * N_POINTS + n];
        int pi = wp[c * N_POINTS + n];
        if (d < bestd) { bestd = d; bpair = pi; }
    }
    int b = n >> 12;
    int hw = n & 4095;
    const float* zp = z + b * 16384 + hw;
    float z0 = zp[0];
    float z1 = zp[CSTRIDE];
    float z2 = zp[2 * CSTRIDE];
    float z3 = zp[3 * CSTRIDE];
    float zz = __fmul_rn(z0, z0);
    zz = __fadd_rn(zz, __fmul_rn(z1, z1));
    zz = __fadd_rn(zz, __fmul_rn(z2, z2));
    zz = __fadd_rn(zz, __fmul_rn(z3, z3));

    // recompute both candidates of the winning pair with the exact scalar chain;
    // lo has the smaller index, so ties go to lo (reference first-index semantics).
    int jl = bpair * 2, jh = jl + 1;
    float4 el = E[jl], eh = E[jh];
    float eel = __fmul_rn(el.x, el.x);
    eel = __fadd_rn(eel, __fmul_rn(el.y, el.y));
    eel = __fadd_rn(eel, __fmul_rn(el.z, el.z));
    eel = __fadd_rn(eel, __fmul_rn(el.w, el.w));
    float dotl = __fmul_rn(z0, el.x);
    dotl = __fmaf_rn(z1, el.y, dotl);
    dotl = __fmaf_rn(z2, el.z, dotl);
    dotl = __fmaf_rn(z3, el.w, dotl);
    float dl = __fmaf_rn(-2.0f, dotl, __fadd_rn(zz, eel));
    float eeh = __fmul_rn(eh.x, eh.x);
    eeh = __fadd_rn(eeh, __fmul_rn(eh.y, eh.y));
    eeh = __fadd_rn(eeh, __fmul_rn(eh.z, eh.z));
    eeh = __fadd_rn(eeh, __fmul_rn(eh.w, eh.w));
    float doth = __fmul_rn(z0, eh.x);
    doth = __fmaf_rn(z1, eh.y, doth);
    doth = __fmaf_rn(z2, eh.z, doth);
    doth = __fmaf_rn(z3, eh.w, doth);
    float dh = __fmaf_rn(-2.0f, doth, __fadd_rn(zz, eeh));

    int besti; float4 e;
    if (dh < dl) { besti = jh; e = eh; } else { besti = jl; e = el; }

    float* op = out + b * 16384 + hw;
    float ec[4] = {e.x, e.y, e.z, e.w};
    float zc[4] = {z0, z1, z2, z3};
    double ds = 0.0;
    #pragma unroll
    for (int cc = 0; cc < 4; ++cc) {
        float t = __fsub_rn(ec[cc], zc[cc]);     // z_q - z (the sg'd diff, also loss diff)
        float q = __fadd_rn(zc[cc], t);          // straight-through: z + (z_q - z)
        op[cc * CSTRIDE] = q;
        float t2 = __fmul_rn(t, t);
        ds += (double)t2;
    }
    out[131073 + n] = (float)besti;              // indices as float32 (exact)

    sdata[threadIdx.x] = ds;
    __syncthreads();
    #pragma unroll
    for (int s = 128; s > 0; s >>= 1) {
        if (threadIdx.x < s) sdata[threadIdx.x] += sdata[threadIdx.x + s];
        __syncthreads();
    }
    if (threadIdx.x == 0) partial[blockIdx.x] = sdata[0];
}

// ---------------- kernel D: deterministic loss reduce
__global__ void vq_loss_kernel(const double* __restrict__ partial, float* __restrict__ out) {
    __shared__ double sdata[128];
    int t = threadIdx.x;
    sdata[t] = partial[t];
    __syncthreads();
    #pragma unroll
    for (int s = 64; s > 0; s >>= 1) {
        if (t < s) sdata[t] += sdata[t + s];
        __syncthreads();
    }
    if (t == 0) {
        float m = (float)(sdata[0] / 131072.0);
        // loss = mean + BETA*mean (both means are numerically identical)
        out[131072] = __fadd_rn(m, __fmul_rn(0.25f, m));
    }
}

extern "C" void kernel_launch(void* const* d_in, const int* in_sizes, int n_in,
                              void* d_out, int out_size, void* d_ws, size_t ws_size,
                              hipStream_t stream) {
    const float* z = (const float*)d_in[0];
    const float4* E = (const float4*)d_in[1];
    float* out = (float*)d_out;

    char* ws = (char*)d_ws;
    v2f* Epk = (v2f*)ws;                                     // 4096*4 v2f = 128 KB
    v2f* eev = (v2f*)(ws + 131072);                          // 4096 v2f = 32 KB
    const size_t base = 131072 + 32768;

    vq_prep_kernel<<<NPAIRS / 256, 256, 0, stream>>>(E, Epk, eev);

    const size_t need32 = base + (size_t)32 * N_POINTS * 8 + 1024;   // ~8.4 MB
    if (ws_size >= need32) {
        float* wd = (float*)(ws + base);                                     // 4 MB
        int*   wp = (int*)(ws + base + (size_t)32 * N_POINTS * 4);           // 4 MB
        double* partial = (double*)(ws + base + (size_t)32 * N_POINTS * 8);  // 1 KB
        vq_partial_kernel<32><<<dim3(N_POINTS / (256 * PPT), 32), 256, 0, stream>>>(
            z, Epk, eev, wd, wp);
        vq_finalize_kernel<32><<<N_POINTS / 256, 256, 0, stream>>>(z, E, wd, wp, out, partial);
    } else {
        float* wd = (float*)(ws + base);                                     // 2 MB
        int*   wp = (int*)(ws + base + (size_t)16 * N_POINTS * 4);           // 2 MB
        double* partial = (double*)(ws + base + (size_t)16 * N_POINTS * 8);  // 1 KB
        vq_partial_kernel<16><<<dim3(N_POINTS / (256 * PPT), 16), 256, 0, stream>>>(
            z, Epk, eev, wd, wp);
        vq_finalize_kernel<16><<<N_POINTS / 256, 256, 0, stream>>>(z, E, wd, wp, out, partial);
    }
    vq_loss_kernel<<<1, 128, 0, stream>>>(
        (double*)(ws + base + (ws_size >= need32 ? (size_t)32 : (size_t)16) * N_POINTS * 8), out);
}

// Round 7
// 74.239 us; speedup vs baseline: 1.0495x; 1.0495x over previous
//
#include <hip/hip_runtime.h>
#include <math.h>

typedef float v2f __attribute__((ext_vector_type(2)));

#define N_POINTS 32768
#define NUM_EMBED 8192
#define NPAIRS 4096
#define PPT 4                                // points per thread (amortizes LDS broadcasts)
#define CSTRIDE 4096                         // 64*64, channel stride in z [B,C,H,W]

// ---------------- kernel A: build pair-interleaved codebook + ee (exact XLA arithmetic)
__global__ void vq_prep_kernel(const float4* __restrict__ E,
                               v2f* __restrict__ Epk, v2f* __restrict__ eev) {
    int p = blockIdx.x * 256 + threadIdx.x;
    if (p < NPAIRS) {
        float4 a = E[2 * p];
        float4 b = E[2 * p + 1];
        Epk[4 * p + 0] = (v2f){a.x, b.x};
        Epk[4 * p + 1] = (v2f){a.y, b.y};
        Epk[4 * p + 2] = (v2f){a.z, b.z};
        Epk[4 * p + 3] = (v2f){a.w, b.w};
        float ea = __fmul_rn(a.x, a.x);
        ea = __fadd_rn(ea, __fmul_rn(a.y, a.y));
        ea = __fadd_rn(ea, __fmul_rn(a.z, a.z));
        ea = __fadd_rn(ea, __fmul_rn(a.w, a.w));
        float eb = __fmul_rn(b.x, b.x);
        eb = __fadd_rn(eb, __fmul_rn(b.y, b.y));
        eb = __fadd_rn(eb, __fmul_rn(b.z, b.z));
        eb = __fadd_rn(eb, __fmul_rn(b.w, b.w));
        eev[p] = (v2f){ea, eb};
    }
}

// packed f32 ops forced via inline asm (per-half IEEE rn, bit-identical to scalar chain)
__device__ __forceinline__ v2f pk_add(v2f a, v2f b) {
    v2f d; asm("v_pk_add_f32 %0, %1, %2" : "=v"(d) : "v"(a), "v"(b)); return d;
}
__device__ __forceinline__ v2f pk_mul(v2f a, v2f b) {
    v2f d; asm("v_pk_mul_f32 %0, %1, %2" : "=v"(d) : "v"(a), "v"(b)); return d;
}
__device__ __forceinline__ v2f pk_fma(v2f a, v2f b, v2f c) {
    v2f d; asm("v_pk_fma_f32 %0, %1, %2, %3" : "=v"(d) : "v"(a), "v"(b), "v"(c)); return d;
}

// ---------------- kernel B: per (point, chunk) PAIR-granularity argmin
// Tracks (min value, pair id) with strict < (first pair wins); packed (d, pair) float2 out.
template<int CH>
__global__ __launch_bounds__(256) void vq_partial_kernel(
        const float* __restrict__ z, const v2f* __restrict__ Epk,
        const v2f* __restrict__ eev,
        float2* __restrict__ wdp) {
    constexpr int PAIRS = NPAIRS / CH;
    __shared__ alignas(16) v2f sE[PAIRS * 4];
    __shared__ alignas(16) v2f see[PAIRS];

    const int c = blockIdx.y;

    // ---- stage chunk slice to LDS (coalesced float4 vector loads)
    {
        const float4* gE = (const float4*)(Epk + (size_t)c * PAIRS * 4); // PAIRS*2 float4
        float4* sw = (float4*)sE;
        #pragma unroll
        for (int i = 0; i < (PAIRS * 2) / 256; ++i)
            sw[i * 256 + threadIdx.x] = gE[i * 256 + threadIdx.x];
        if (threadIdx.x < PAIRS / 2) {
            ((float4*)see)[threadIdx.x] =
                ((const float4*)(eev + (size_t)c * PAIRS))[threadIdx.x];
        }
    }

    const int n0 = blockIdx.x * (256 * PPT) + threadIdx.x;

    // ---- load PPT points; zz via mul + sequential adds (matches reference exactly)
    v2f zv[PPT][4], zzv[PPT];
    #pragma unroll
    for (int p = 0; p < PPT; ++p) {
        int n = n0 + p * 256;
        int b = n >> 12, hw = n & 4095;
        const float* zp = z + b * 16384 + hw;
        float a0 = zp[0], a1 = zp[CSTRIDE], a2 = zp[2 * CSTRIDE], a3 = zp[3 * CSTRIDE];
        float zz = __fmul_rn(a0, a0);
        zz = __fadd_rn(zz, __fmul_rn(a1, a1));
        zz = __fadd_rn(zz, __fmul_rn(a2, a2));
        zz = __fadd_rn(zz, __fmul_rn(a3, a3));
        zv[p][0] = (v2f){a0, a0}; zv[p][1] = (v2f){a1, a1};
        zv[p][2] = (v2f){a2, a2}; zv[p][3] = (v2f){a3, a3};
        zzv[p] = (v2f){zz, zz};
    }
    const v2f m2v = {-2.0f, -2.0f};

    __syncthreads();

    float bd[PPT]; int bp[PPT];
    #pragma unroll
    for (int p = 0; p < PPT; ++p) { bd[p] = __builtin_inff(); bp[p] = 0; }

    const float4* sE4 = (const float4*)sE;
    #pragma unroll 2
    for (int t = 0; t < PAIRS; ++t) {
        // uniform LDS reads -> hardware broadcast, no bank conflicts
        float4 E01 = sE4[2 * t];       // {e0.lo,e0.hi, e1.lo,e1.hi}
        float4 E23 = sE4[2 * t + 1];   // {e2.lo,e2.hi, e3.lo,e3.hi}
        v2f ee2 = see[t];
        v2f e0 = {E01.x, E01.y};
        v2f e1 = {E01.z, E01.w};
        v2f e2 = {E23.x, E23.y};
        v2f e3 = {E23.z, E23.w};
        #pragma unroll
        for (int p = 0; p < PPT; ++p) {
            // per-half arithmetic identical to the scalar reference chain:
            v2f szz = pk_add(zzv[p], ee2);        // zz + ee_j         (rn)
            v2f dot = pk_mul(zv[p][0], e0);       // z0*e0             (rn)
            dot = pk_fma(zv[p][1], e1, dot);      // ascending-k fma chain
            dot = pk_fma(zv[p][2], e2, dot);
            dot = pk_fma(zv[p][3], e3, dot);
            v2f d2 = pk_fma(m2v, dot, szz);       // (zz+ee) - 2*dot (2*dot exact)
            float md = fminf(d2.x, d2.y);         // exact selection (no NaNs)
            if (md < bd[p]) { bd[p] = md; bp[p] = t; }  // strict <: first pair wins
        }
    }

    const int pbase = c * PAIRS;
    #pragma unroll
    for (int p = 0; p < PPT; ++p) {
        int n = n0 + p * 256;
        wdp[c * N_POINTS + n] = make_float2(bd[p], __int_as_float(pbase + bp[p]));
    }
}

// ---------------- kernel C: combine chunks, resolve pair exactly, write outputs
template<int CH>
__global__ __launch_bounds__(256) void vq_finalize_kernel(
        const float* __restrict__ z, const float4* __restrict__ E,
        const float2* __restrict__ wdp,
        float* __restrict__ out, double* __restrict__ partial) {
    __shared__ double sdata[256];
    int n = blockIdx.x * 256 + threadIdx.x;
    float bestd = __builtin_inff();
    int bpair = 0;
    #pragma unroll 4
    for (int c = 0; c < CH; ++c) {               // ascending chunk + strict < -> first pair
        float2 v = wdp[c * N_POINTS + n];
        if (v.x < bestd) { bestd = v.x; bpair = __float_as_int(v.y); }
    }
    int b = n >> 12;
    int hw = n & 4095;
    const float* zp = z + b * 16384 + hw;
    float z0 = zp[0];
    float z1 = zp[CSTRIDE];
    float z2 = zp[2 * CSTRIDE];
    float z3 = zp[3 * CSTRIDE];
    float zz = __fmul_rn(z0, z0);
    zz = __fadd_rn(zz, __fmul_rn(z1, z1));
    zz = __fadd_rn(zz, __fmul_rn(z2, z2));
    zz = __fadd_rn(zz, __fmul_rn(z3, z3));

    // recompute both candidates of the winning pair with the exact scalar chain;
    // lo has the smaller index, so ties go to lo (reference first-index semantics).
    int jl = bpair * 2, jh = jl + 1;
    float4 el = E[jl], eh = E[jh];
    float eel = __fmul_rn(el.x, el.x);
    eel = __fadd_rn(eel, __fmul_rn(el.y, el.y));
    eel = __fadd_rn(eel, __fmul_rn(el.z, el.z));
    eel = __fadd_rn(eel, __fmul_rn(el.w, el.w));
    float dotl = __fmul_rn(z0, el.x);
    dotl = __fmaf_rn(z1, el.y, dotl);
    dotl = __fmaf_rn(z2, el.z, dotl);
    dotl = __fmaf_rn(z3, el.w, dotl);
    float dl = __fmaf_rn(-2.0f, dotl, __fadd_rn(zz, eel));
    float eeh = __fmul_rn(eh.x, eh.x);
    eeh = __fadd_rn(eeh, __fmul_rn(eh.y, eh.y));
    eeh = __fadd_rn(eeh, __fmul_rn(eh.z, eh.z));
    eeh = __fadd_rn(eeh, __fmul_rn(eh.w, eh.w));
    float doth = __fmul_rn(z0, eh.x);
    doth = __fmaf_rn(z1, eh.y, doth);
    doth = __fmaf_rn(z2, eh.z, doth);
    doth = __fmaf_rn(z3, eh.w, doth);
    float dh = __fmaf_rn(-2.0f, doth, __fadd_rn(zz, eeh));

    int besti; float4 e;
    if (dh < dl) { besti = jh; e = eh; } else { besti = jl; e = el; }

    float* op = out + b * 16384 + hw;
    float ec[4] = {e.x, e.y, e.z, e.w};
    float zc[4] = {z0, z1, z2, z3};
    double ds = 0.0;
    #pragma unroll
    for (int cc = 0; cc < 4; ++cc) {
        float t = __fsub_rn(ec[cc], zc[cc]);     // z_q - z (the sg'd diff, also loss diff)
        float q = __fadd_rn(zc[cc], t);          // straight-through: z + (z_q - z)
        op[cc * CSTRIDE] = q;
        float t2 = __fmul_rn(t, t);
        ds += (double)t2;
    }
    out[131073 + n] = (float)besti;              // indices as float32 (exact)

    sdata[threadIdx.x] = ds;
    __syncthreads();
    #pragma unroll
    for (int s = 128; s > 0; s >>= 1) {
        if (threadIdx.x < s) sdata[threadIdx.x] += sdata[threadIdx.x + s];
        __syncthreads();
    }
    if (threadIdx.x == 0) partial[blockIdx.x] = sdata[0];
}

// ---------------- kernel D: deterministic loss reduce
__global__ void vq_loss_kernel(const double* __restrict__ partial, float* __restrict__ out) {
    __shared__ double sdata[128];
    int t = threadIdx.x;
    sdata[t] = partial[t];
    __syncthreads();
    #pragma unroll
    for (int s = 64; s > 0; s >>= 1) {
        if (t < s) sdata[t] += sdata[t + s];
        __syncthreads();
    }
    if (t == 0) {
        float m = (float)(sdata[0] / 131072.0);
        // loss = mean + BETA*mean (both means are numerically identical)
        out[131072] = __fadd_rn(m, __fmul_rn(0.25f, m));
    }
}

extern "C" void kernel_launch(void* const* d_in, const int* in_sizes, int n_in,
                              void* d_out, int out_size, void* d_ws, size_t ws_size,
                              hipStream_t stream) {
    const float* z = (const float*)d_in[0];
    const float4* E = (const float4*)d_in[1];
    float* out = (float*)d_out;

    char* ws = (char*)d_ws;
    v2f* Epk = (v2f*)ws;                                     // 4096*4 v2f = 128 KB
    v2f* eev = (v2f*)(ws + 131072);                          // 4096 v2f = 32 KB
    const size_t base = 131072 + 32768;

    vq_prep_kernel<<<NPAIRS / 256, 256, 0, stream>>>(E, Epk, eev);

    const size_t need32 = base + (size_t)32 * N_POINTS * 8 + 1024;   // ~8.6 MB
    if (ws_size >= need32) {
        float2* wdp = (float2*)(ws + base);                                  // 8 MB
        double* partial = (double*)(ws + base + (size_t)32 * N_POINTS * 8);  // 1 KB
        vq_partial_kernel<32><<<dim3(N_POINTS / (256 * PPT), 32), 256, 0, stream>>>(
            z, Epk, eev, wdp);
        vq_finalize_kernel<32><<<N_POINTS / 256, 256, 0, stream>>>(z, E, wdp, out, partial);
        vq_loss_kernel<<<1, 128, 0, stream>>>(partial, out);
    } else {
        float2* wdp = (float2*)(ws + base);                                  // 4 MB
        double* partial = (double*)(ws + base + (size_t)16 * N_POINTS * 8);  // 1 KB
        vq_partial_kernel<16><<<dim3(N_POINTS / (256 * PPT), 16), 256, 0, stream>>>(
            z, Epk, eev, wdp);
        vq_finalize_kernel<16><<<N_POINTS / 256, 256, 0, stream>>>(z, E, wdp, out, partial);
        vq_loss_kernel<<<1, 128, 0, stream>>>(partial, out);
    }
}

// Round 8
// 62.182 us; speedup vs baseline: 1.2530x; 1.1939x over previous
//
#include <hip/hip_runtime.h>
#include <math.h>

typedef float v2f __attribute__((ext_vector_type(2)));

#define N_POINTS 32768
#define NUM_EMBED 8192
#define NPAIRS 4096
#define CH 64                                // chunks -> grid 32x64 = 2048 blocks (8/CU)
#define PAIRS (NPAIRS / CH)                  // 64 pairs (128 candidates) per chunk
#define PPT 4                                // points per thread (amortizes LDS broadcasts)
#define CSTRIDE 4096                         // 64*64, channel stride in z [B,C,H,W]

// ---------------- kernel A0: init per-point atomic keys to +inf
__global__ void vq_init_kernel(unsigned long long* __restrict__ keys) {
    int i = blockIdx.x * 256 + threadIdx.x;
    keys[i] = ~0ULL;
}

// ---------------- kernel A: build pair-interleaved codebook + ee (exact XLA arithmetic)
__global__ void vq_prep_kernel(const float4* __restrict__ E,
                               v2f* __restrict__ Epk, v2f* __restrict__ eev) {
    int p = blockIdx.x * 256 + threadIdx.x;
    if (p < NPAIRS) {
        float4 a = E[2 * p];
        float4 b = E[2 * p + 1];
        Epk[4 * p + 0] = (v2f){a.x, b.x};
        Epk[4 * p + 1] = (v2f){a.y, b.y};
        Epk[4 * p + 2] = (v2f){a.z, b.z};
        Epk[4 * p + 3] = (v2f){a.w, b.w};
        float ea = __fmul_rn(a.x, a.x);
        ea = __fadd_rn(ea, __fmul_rn(a.y, a.y));
        ea = __fadd_rn(ea, __fmul_rn(a.z, a.z));
        ea = __fadd_rn(ea, __fmul_rn(a.w, a.w));
        float eb = __fmul_rn(b.x, b.x);
        eb = __fadd_rn(eb, __fmul_rn(b.y, b.y));
        eb = __fadd_rn(eb, __fmul_rn(b.z, b.z));
        eb = __fadd_rn(eb, __fmul_rn(b.w, b.w));
        eev[p] = (v2f){ea, eb};
    }
}

// packed f32 ops forced via inline asm (per-half IEEE rn, bit-identical to scalar chain)
__device__ __forceinline__ v2f pk_add(v2f a, v2f b) {
    v2f d; asm("v_pk_add_f32 %0, %1, %2" : "=v"(d) : "v"(a), "v"(b)); return d;
}
__device__ __forceinline__ v2f pk_mul(v2f a, v2f b) {
    v2f d; asm("v_pk_mul_f32 %0, %1, %2" : "=v"(d) : "v"(a), "v"(b)); return d;
}
__device__ __forceinline__ v2f pk_fma(v2f a, v2f b, v2f c) {
    v2f d; asm("v_pk_fma_f32 %0, %1, %2, %3" : "=v"(d) : "v"(a), "v"(b), "v"(c)); return d;
}

// order-preserving bijection float -> uint32 (handles negatives; total order == float <)
__device__ __forceinline__ unsigned int fkey(float f) {
    unsigned int b = __float_as_uint(f);
    return b ^ (0x80000000u | (unsigned int)((int)b >> 31));
}

// ---------------- kernel B: per (point, chunk) PAIR-granularity argmin -> atomicMin key
// Tracks (min value, pair id) with strict < (first pair wins). Key = (fkey(d)<<32)|pair:
// atomicMin is order-independent and keeps smallest pair at equal d (first-index safe).
__global__ __launch_bounds__(256) void vq_partial_kernel(
        const float* __restrict__ z, const v2f* __restrict__ Epk,
        const v2f* __restrict__ eev,
        unsigned long long* __restrict__ keys) {
    __shared__ alignas(16) v2f sE[PAIRS * 4];   // 2 KB
    __shared__ alignas(16) v2f see[PAIRS];      // 512 B

    const int c = blockIdx.y;

    // ---- stage chunk slice to LDS (coalesced float4 vector loads): 128 + 32 float4
    {
        const float4* gE = (const float4*)(Epk + (size_t)c * PAIRS * 4);
        if (threadIdx.x < PAIRS * 2) {
            ((float4*)sE)[threadIdx.x] = gE[threadIdx.x];
        } else if (threadIdx.x < PAIRS * 2 + PAIRS / 2) {
            ((float4*)see)[threadIdx.x - PAIRS * 2] =
                ((const float4*)(eev + (size_t)c * PAIRS))[threadIdx.x - PAIRS * 2];
        }
    }

    const int n0 = blockIdx.x * (256 * PPT) + threadIdx.x;

    // ---- load PPT points; zz via mul + sequential adds (matches reference exactly)
    v2f zv[PPT][4], zzv[PPT];
    #pragma unroll
    for (int p = 0; p < PPT; ++p) {
        int n = n0 + p * 256;
        int b = n >> 12, hw = n & 4095;
        const float* zp = z + b * 16384 + hw;
        float a0 = zp[0], a1 = zp[CSTRIDE], a2 = zp[2 * CSTRIDE], a3 = zp[3 * CSTRIDE];
        float zz = __fmul_rn(a0, a0);
        zz = __fadd_rn(zz, __fmul_rn(a1, a1));
        zz = __fadd_rn(zz, __fmul_rn(a2, a2));
        zz = __fadd_rn(zz, __fmul_rn(a3, a3));
        zv[p][0] = (v2f){a0, a0}; zv[p][1] = (v2f){a1, a1};
        zv[p][2] = (v2f){a2, a2}; zv[p][3] = (v2f){a3, a3};
        zzv[p] = (v2f){zz, zz};
    }
    const v2f m2v = {-2.0f, -2.0f};

    __syncthreads();

    float bd[PPT]; int bp[PPT];
    #pragma unroll
    for (int p = 0; p < PPT; ++p) { bd[p] = __builtin_inff(); bp[p] = 0; }

    const float4* sE4 = (const float4*)sE;
    #pragma unroll 4
    for (int t = 0; t < PAIRS; ++t) {
        // uniform LDS reads -> hardware broadcast, no bank conflicts
        float4 E01 = sE4[2 * t];       // {e0.lo,e0.hi, e1.lo,e1.hi}
        float4 E23 = sE4[2 * t + 1];   // {e2.lo,e2.hi, e3.lo,e3.hi}
        v2f ee2 = see[t];
        v2f e0 = {E01.x, E01.y};
        v2f e1 = {E01.z, E01.w};
        v2f e2 = {E23.x, E23.y};
        v2f e3 = {E23.z, E23.w};
        #pragma unroll
        for (int p = 0; p < PPT; ++p) {
            // per-half arithmetic identical to the scalar reference chain:
            v2f szz = pk_add(zzv[p], ee2);        // zz + ee_j         (rn)
            v2f dot = pk_mul(zv[p][0], e0);       // z0*e0             (rn)
            dot = pk_fma(zv[p][1], e1, dot);      // ascending-k fma chain
            dot = pk_fma(zv[p][2], e2, dot);
            dot = pk_fma(zv[p][3], e3, dot);
            v2f d2 = pk_fma(m2v, dot, szz);       // (zz+ee) - 2*dot (2*dot exact)
            float md = fminf(d2.x, d2.y);         // exact selection (no NaNs)
            if (md < bd[p]) { bd[p] = md; bp[p] = t; }  // strict <: first pair wins
        }
    }

    const int pbase = c * PAIRS;
    #pragma unroll
    for (int p = 0; p < PPT; ++p) {
        int n = n0 + p * 256;
        unsigned long long key =
            ((unsigned long long)fkey(bd[p]) << 32) | (unsigned int)(pbase + bp[p]);
        atomicMin(&keys[n], key);
    }
}

// ---------------- kernel C: resolve winning pair exactly, write outputs + loss partials
__global__ __launch_bounds__(256) void vq_finalize_kernel(
        const float* __restrict__ z, const float4* __restrict__ E,
        const unsigned long long* __restrict__ keys,
        float* __restrict__ out, double* __restrict__ partial) {
    __shared__ double sdata[256];
    int n = blockIdx.x * 256 + threadIdx.x;
    int bpair = (int)(unsigned int)(keys[n] & 0xFFFFFFFFull);

    int b = n >> 12;
    int hw = n & 4095;
    const float* zp = z + b * 16384 + hw;
    float z0 = zp[0];
    float z1 = zp[CSTRIDE];
    float z2 = zp[2 * CSTRIDE];
    float z3 = zp[3 * CSTRIDE];
    float zz = __fmul_rn(z0, z0);
    zz = __fadd_rn(zz, __fmul_rn(z1, z1));
    zz = __fadd_rn(zz, __fmul_rn(z2, z2));
    zz = __fadd_rn(zz, __fmul_rn(z3, z3));

    // recompute both candidates of the winning pair with the exact scalar chain;
    // lo has the smaller index, so ties go to lo (reference first-index semantics).
    int jl = bpair * 2, jh = jl + 1;
    float4 el = E[jl], eh = E[jh];
    float eel = __fmul_rn(el.x, el.x);
    eel = __fadd_rn(eel, __fmul_rn(el.y, el.y));
    eel = __fadd_rn(eel, __fmul_rn(el.z, el.z));
    eel = __fadd_rn(eel, __fmul_rn(el.w, el.w));
    float dotl = __fmul_rn(z0, el.x);
    dotl = __fmaf_rn(z1, el.y, dotl);
    dotl = __fmaf_rn(z2, el.z, dotl);
    dotl = __fmaf_rn(z3, el.w, dotl);
    float dl = __fmaf_rn(-2.0f, dotl, __fadd_rn(zz, eel));
    float eeh = __fmul_rn(eh.x, eh.x);
    eeh = __fadd_rn(eeh, __fmul_rn(eh.y, eh.y));
    eeh = __fadd_rn(eeh, __fmul_rn(eh.z, eh.z));
    eeh = __fadd_rn(eeh, __fmul_rn(eh.w, eh.w));
    float doth = __fmul_rn(z0, eh.x);
    doth = __fmaf_rn(z1, eh.y, doth);
    doth = __fmaf_rn(z2, eh.z, doth);
    doth = __fmaf_rn(z3, eh.w, doth);
    float dh = __fmaf_rn(-2.0f, doth, __fadd_rn(zz, eeh));

    int besti; float4 e;
    if (dh < dl) { besti = jh; e = eh; } else { besti = jl; e = el; }

    float* op = out + b * 16384 + hw;
    float ec[4] = {e.x, e.y, e.z, e.w};
    float zc[4] = {z0, z1, z2, z3};
    double ds = 0.0;
    #pragma unroll
    for (int cc = 0; cc < 4; ++cc) {
        float t = __fsub_rn(ec[cc], zc[cc]);     // z_q - z (the sg'd diff, also loss diff)
        float q = __fadd_rn(zc[cc], t);          // straight-through: z + (z_q - z)
        op[cc * CSTRIDE] = q;
        float t2 = __fmul_rn(t, t);
        ds += (double)t2;
    }
    out[131073 + n] = (float)besti;              // indices as float32 (exact)

    sdata[threadIdx.x] = ds;
    __syncthreads();
    #pragma unroll
    for (int s = 128; s > 0; s >>= 1) {
        if (threadIdx.x < s) sdata[threadIdx.x] += sdata[threadIdx.x + s];
        __syncthreads();
    }
    if (threadIdx.x == 0) partial[blockIdx.x] = sdata[0];
}

// ---------------- kernel D: deterministic loss reduce
__global__ void vq_loss_kernel(const double* __restrict__ partial, float* __restrict__ out) {
    __shared__ double sdata[128];
    int t = threadIdx.x;
    sdata[t] = partial[t];
    __syncthreads();
    #pragma unroll
    for (int s = 64; s > 0; s >>= 1) {
        if (t < s) sdata[t] += sdata[t + s];
        __syncthreads();
    }
    if (t == 0) {
        float m = (float)(sdata[0] / 131072.0);
        // loss = mean + BETA*mean (both means are numerically identical)
        out[131072] = __fadd_rn(m, __fmul_rn(0.25f, m));
    }
}

extern "C" void kernel_launch(void* const* d_in, const int* in_sizes, int n_in,
                              void* d_out, int out_size, void* d_ws, size_t ws_size,
                              hipStream_t stream) {
    const float* z = (const float*)d_in[0];
    const float4* E = (const float4*)d_in[1];
    float* out = (float*)d_out;

    char* ws = (char*)d_ws;
    v2f* Epk = (v2f*)ws;                                         // 128 KB
    v2f* eev = (v2f*)(ws + 131072);                              // 32 KB
    unsigned long long* keys = (unsigned long long*)(ws + 163840);   // 256 KB
    double* partial = (double*)(ws + 163840 + 262144);               // 1 KB

    vq_init_kernel<<<N_POINTS / 256, 256, 0, stream>>>(keys);
    vq_prep_kernel<<<NPAIRS / 256, 256, 0, stream>>>(E, Epk, eev);
    vq_partial_kernel<<<dim3(N_POINTS / (256 * PPT), CH), 256, 0, stream>>>(z, Epk, eev, keys);
    vq_finalize_kernel<<<N_POINTS / 256, 256, 0, stream>>>(z, E, keys, out, partial);
    vq_loss_kernel<<<1, 128, 0, stream>>>(partial, out);
}